// Round 6
// baseline (491.192 us; speedup 1.0000x reference)
//
#include <hip/hip_runtime.h>
#include <math.h>

#define N_NODES 20000
#define N_EDGES 160000
#define NODE_DIM 64
#define EDGE_DIM 16
#define H 32
#define STEPS 3
#define UROW 544   // U[v][c]: c = i*16+d for c<512 (i=c>>4,d=c&15); c=512+i is bias plane
#define NBLK 79    // ceil(20000/256)

// ---------------------------------------------------------------------------
// One-time build: src-CSR (rowptrS) for streaming, dst-CSR (rowptrD) for the
// gather, pos[j] = dst-sorted slot of src-sorted edge j, ef2 = ef permuted
// into src-sorted order. hist -> 2-array scan -> fill -> pos -> permute.
// ---------------------------------------------------------------------------
__global__ void hist2_kernel(const int* __restrict__ ei,
                             int* __restrict__ degS, int* __restrict__ degD) {
    int e = blockIdx.x * 256 + threadIdx.x;
    if (e < N_EDGES) {
        atomicAdd(&degS[ei[e]], 1);
        atomicAdd(&degD[ei[N_EDGES + e]], 1);
    }
}

// grid (NBLK, 2): y=0 scans degS->rowptrS, y=1 scans degD->rowptrD
__global__ void scan_a_kernel(const int* __restrict__ degS,
                              const int* __restrict__ degD,
                              int* __restrict__ rowptrS,
                              int* __restrict__ rowptrD,
                              int* __restrict__ bsum) {
    __shared__ int s[256];
    const int* deg = blockIdx.y ? degD : degS;
    int* part      = blockIdx.y ? rowptrD : rowptrS;
    int v = blockIdx.x * 256 + threadIdx.x;
    int x = (v < N_NODES) ? deg[v] : 0;
    s[threadIdx.x] = x;
    __syncthreads();
    for (int off = 1; off < 256; off <<= 1) {
        int t = (threadIdx.x >= off) ? s[threadIdx.x - off] : 0;
        __syncthreads();
        s[threadIdx.x] += t;
        __syncthreads();
    }
    if (v < N_NODES) part[v] = s[threadIdx.x] - x;
    if (threadIdx.x == 255) bsum[blockIdx.y * NBLK + blockIdx.x] = s[255];
}

// single block: finish both scans, seed both cursors
__global__ void scan_b_kernel(int* __restrict__ rowptrS,
                              int* __restrict__ rowptrD,
                              const int* __restrict__ bsum,
                              int* __restrict__ cursorS,
                              int* __restrict__ cursorD) {
    __shared__ int boff[2 * NBLK];
    if (threadIdx.x == 0) {
        for (int a = 0; a < 2; ++a) {
            int run = 0;
            for (int b = 0; b < NBLK; ++b) {
                boff[a * NBLK + b] = run;
                run += bsum[a * NBLK + b];
            }
        }
    }
    __syncthreads();
    for (int v = threadIdx.x; v < N_NODES; v += 256) {
        int rs = rowptrS[v] + boff[v >> 8];
        int rd = rowptrD[v] + boff[NBLK + (v >> 8)];
        rowptrS[v] = rs; cursorS[v] = rs;
        rowptrD[v] = rd; cursorD[v] = rd;
    }
    if (threadIdx.x == 0) {
        rowptrS[N_NODES] = N_EDGES;
        rowptrD[N_NODES] = N_EDGES;
    }
}

__global__ void fill_kernel(const int* __restrict__ ei, int* __restrict__ cursorS,
                            int* __restrict__ eperm, int* __restrict__ dst2) {
    int e = blockIdx.x * 256 + threadIdx.x;
    if (e < N_EDGES) {
        int s = ei[e];
        int slot = atomicAdd(&cursorS[s], 1);
        eperm[slot] = e;
        dst2[slot]  = ei[N_EDGES + e];
    }
}

__global__ void pos_kernel(const int* __restrict__ dst2, int* __restrict__ cursorD,
                           int* __restrict__ pos) {
    int j = blockIdx.x * 256 + threadIdx.x;
    if (j < N_EDGES) pos[j] = atomicAdd(&cursorD[dst2[j]], 1);
}

__global__ void permute_ef_kernel(const float* __restrict__ ef,
                                  const int* __restrict__ eperm,
                                  float* __restrict__ ef2) {
    int t = blockIdx.x * 256 + threadIdx.x;
    if (t < N_EDGES * EDGE_DIM) {
        int j = t >> 4;
        int d = t & 15;
        ef2[t] = ef[eperm[j] * EDGE_DIM + d];
    }
}

// ---------------------------------------------------------------------------
// node projection: h = node_feat @ W_np.T + b_np
// ---------------------------------------------------------------------------
__global__ void node_proj_kernel(const float* __restrict__ nf,
                                 const float* __restrict__ W,
                                 const float* __restrict__ b,
                                 float* __restrict__ h) {
    int tid = blockIdx.x * blockDim.x + threadIdx.x;
    if (tid >= N_NODES * H) return;
    int v = tid >> 5;
    int i = tid & 31;
    const float* __restrict__ row = nf + v * NODE_DIM;
    const float* __restrict__ w   = W + i * NODE_DIM;
    float acc = b[i];
#pragma unroll
    for (int d = 0; d < NODE_DIM; ++d) acc = fmaf(row[d], w[d], acc);
    h[tid] = acc;
}

// ---------------------------------------------------------------------------
// U precompute v3 (unchanged — measured adequate):
//   U[v, c] = sum_k Wx[k][c] * h[v,k], W in registers, h via LDS broadcast.
// ---------------------------------------------------------------------------
__global__ __launch_bounds__(576)
void u_precompute_kernel(const float* __restrict__ We,
                         const float* __restrict__ be,
                         const float* __restrict__ h,
                         float* __restrict__ U) {
    __shared__ float hs[32 * 32];   // 4 KB
    int t = threadIdx.x;
    int c = t;

    float wreg[32];
    if (c < 512) {
        int i = c >> 4, d = c & 15;
#pragma unroll
        for (int k = 0; k < H; ++k) wreg[k] = We[(i * H + k) * EDGE_DIM + d];
    } else if (c < UROW) {
        int i = c - 512;
#pragma unroll
        for (int k = 0; k < H; ++k) wreg[k] = be[i * H + k];
    }

    for (int v0 = blockIdx.x * 32; v0 < N_NODES; v0 += gridDim.x * 32) {
        __syncthreads();
        for (int idx = t; idx < 32 * 32; idx += 576) hs[idx] = h[v0 * H + idx];
        __syncthreads();

        for (int n = 0; n < 32; n += 2) {
            const float4* __restrict__ hp0 = (const float4*)(hs + n * H);
            const float4* __restrict__ hp1 = (const float4*)(hs + (n + 1) * H);
            float a0 = 0.f, a1 = 0.f;
#pragma unroll
            for (int kk = 0; kk < 8; ++kk) {
                float4 q0 = hp0[kk];
                float4 q1 = hp1[kk];
                a0 = fmaf(wreg[4 * kk + 0], q0.x, a0);
                a1 = fmaf(wreg[4 * kk + 0], q1.x, a1);
                a0 = fmaf(wreg[4 * kk + 1], q0.y, a0);
                a1 = fmaf(wreg[4 * kk + 1], q1.y, a1);
                a0 = fmaf(wreg[4 * kk + 2], q0.z, a0);
                a1 = fmaf(wreg[4 * kk + 2], q1.z, a1);
                a0 = fmaf(wreg[4 * kk + 3], q0.w, a0);
                a1 = fmaf(wreg[4 * kk + 3], q1.w, a1);
            }
            if (c < UROW) {
                U[(size_t)(v0 + n)     * UROW + c] = a0;
                U[(size_t)(v0 + n + 1) * UROW + c] = a1;
            }
        }
    }
}

// ---------------------------------------------------------------------------
// Edge message v3: group per SRC node, U row in registers (as R5), but the
// result is WRITTEN (not atomically accumulated) to the dst-sorted slot
// pos[j] — plain 128 B store per edge, zero contention.
// ---------------------------------------------------------------------------
__global__ __launch_bounds__(256)
void edge_msg_kernel(const int* __restrict__ rowptrS,
                     const int* __restrict__ pos,
                     const float* __restrict__ ef2,
                     const float* __restrict__ U,
                     float* __restrict__ msg2) {
    int lane = threadIdx.x & 31;
    int s    = (blockIdx.x * blockDim.x + threadIdx.x) >> 5;   // src node
    if (s >= N_NODES) return;

    int e0 = rowptrS[s];
    int e1 = rowptrS[s + 1];
    if (e0 == e1) return;

    const float* __restrict__ Up = U + (size_t)s * UROW;
    const float4* __restrict__ Ur = (const float4*)(Up + lane * EDGE_DIM);
    float4 u0 = Ur[0];
    float4 u1 = Ur[1];
    float4 u2 = Ur[2];
    float4 u3 = Ur[3];
    float bias = Up[512 + lane];

    for (int j = e0; j < e1; ++j) {
        float efv = (lane < EDGE_DIM) ? ef2[j * EDGE_DIM + lane] : 0.f;
        int slot = pos[j];
        float msg = bias;
        msg = fmaf(__shfl(efv,  0, 32), u0.x, msg);
        msg = fmaf(__shfl(efv,  1, 32), u0.y, msg);
        msg = fmaf(__shfl(efv,  2, 32), u0.z, msg);
        msg = fmaf(__shfl(efv,  3, 32), u0.w, msg);
        msg = fmaf(__shfl(efv,  4, 32), u1.x, msg);
        msg = fmaf(__shfl(efv,  5, 32), u1.y, msg);
        msg = fmaf(__shfl(efv,  6, 32), u1.z, msg);
        msg = fmaf(__shfl(efv,  7, 32), u1.w, msg);
        msg = fmaf(__shfl(efv,  8, 32), u2.x, msg);
        msg = fmaf(__shfl(efv,  9, 32), u2.y, msg);
        msg = fmaf(__shfl(efv, 10, 32), u2.z, msg);
        msg = fmaf(__shfl(efv, 11, 32), u2.w, msg);
        msg = fmaf(__shfl(efv, 12, 32), u3.x, msg);
        msg = fmaf(__shfl(efv, 13, 32), u3.y, msg);
        msg = fmaf(__shfl(efv, 14, 32), u3.z, msg);
        msg = fmaf(__shfl(efv, 15, 32), u3.w, msg);
        msg2[(size_t)slot * H + lane] = msg;
    }
}

// ---------------------------------------------------------------------------
// Fused gather + GRU: group per DST node v sums its contiguous dst-sorted
// msg2 slots (coalesced 128 B reads), then applies the GRU inline.
// No m buffer, no atomics, no memset.
// ---------------------------------------------------------------------------
__global__ __launch_bounds__(256)
void gather_gru_kernel(const int* __restrict__ rowptrD,
                       const float* __restrict__ msg2,
                       const float* __restrict__ Wih,
                       const float* __restrict__ Whh,
                       const float* __restrict__ bih,
                       const float* __restrict__ bhh,
                       const float* __restrict__ h,
                       float* __restrict__ hout) {
    __shared__ float WihT[H * 3 * H];   // [k*96 + gate*32 + i] : 12 KB
    __shared__ float WhhT[H * 3 * H];   // 12 KB
    for (int idx = threadIdx.x; idx < 3 * H * H; idx += 256) {
        int row = idx >> 5;
        int k   = idx & 31;
        WihT[k * 96 + row] = Wih[idx];
        WhhT[k * 96 + row] = Whh[idx];
    }
    __syncthreads();

    int lane = threadIdx.x & 31;
    int grp  = threadIdx.x >> 5;

    for (int v0 = blockIdx.x * 8; v0 < N_NODES; v0 += gridDim.x * 8) {
        int v = v0 + grp;
        if (v < N_NODES) {
            int s0 = rowptrD[v];
            int s1 = rowptrD[v + 1];
            float mv = 0.f;
            for (int slot = s0; slot < s1; ++slot)
                mv += msg2[(size_t)slot * H + lane];

            float hv = h[v * H + lane];
            float ir = bih[lane], iz = bih[H + lane], in_ = bih[2 * H + lane];
            float hr = bhh[lane], hz = bhh[H + lane], hn  = bhh[2 * H + lane];
#pragma unroll
            for (int k = 0; k < H; ++k) {
                float mk = __shfl(mv, k, 32);
                float hk = __shfl(hv, k, 32);
                ir  = fmaf(WihT[k * 96 + lane],          mk, ir);
                iz  = fmaf(WihT[k * 96 + H + lane],      mk, iz);
                in_ = fmaf(WihT[k * 96 + 2 * H + lane],  mk, in_);
                hr  = fmaf(WhhT[k * 96 + lane],          hk, hr);
                hz  = fmaf(WhhT[k * 96 + H + lane],      hk, hz);
                hn  = fmaf(WhhT[k * 96 + 2 * H + lane],  hk, hn);
            }
            float r  = 1.f / (1.f + __expf(-(ir + hr)));
            float z  = 1.f / (1.f + __expf(-(iz + hz)));
            float nn = tanhf(in_ + r * hn);
            hout[v * H + lane] = (1.f - z) * nn + z * hv;
        }
    }
}

// ---------------------------------------------------------------------------
extern "C" void kernel_launch(void* const* d_in, const int* in_sizes, int n_in,
                              void* d_out, int out_size, void* d_ws, size_t ws_size,
                              hipStream_t stream) {
    const float* node_feat = (const float*)d_in[0];
    const int*   edge_idx  = (const int*)  d_in[1];
    const float* edge_feat = (const float*)d_in[2];
    const float* W_np      = (const float*)d_in[3];
    const float* b_np      = (const float*)d_in[4];
    const float* W_e       = (const float*)d_in[5];
    const float* b_e       = (const float*)d_in[6];
    const float* W_ih      = (const float*)d_in[7];
    const float* W_hh      = (const float*)d_in[8];
    const float* b_ih      = (const float*)d_in[9];
    const float* b_hh      = (const float*)d_in[10];

    float* h       = (float*)d_ws;                          // N*H
    float* U       = h + (size_t)N_NODES * H;               // N*544
    float* ef2     = U + (size_t)N_NODES * UROW;            // E*16
    float* msg2    = ef2 + (size_t)N_EDGES * EDGE_DIM;      // E*32
    int*   rowptrS = (int*)(msg2 + (size_t)N_EDGES * H);    // N+1
    int*   rowptrD = rowptrS + (N_NODES + 1);               // N+1
    int*   cursorS = rowptrD + (N_NODES + 1);               // N  (also degS)
    int*   cursorD = cursorS + N_NODES;                     // N  (also degD)
    int*   bsum    = cursorD + N_NODES;                     // 2*NBLK
    int*   eperm   = bsum + 2 * NBLK;                       // E
    int*   dst2    = eperm + N_EDGES;                       // E
    int*   pos     = dst2 + N_EDGES;                        // E
    float* out     = (float*)d_out;

    // ---- one-time: build src-CSR, dst-CSR, pos permutation, ef2 ----
    hipMemsetAsync(cursorS, 0, 2 * N_NODES * sizeof(int), stream);  // S+D adjacent
    hist2_kernel<<<(N_EDGES + 255) / 256, 256, 0, stream>>>(edge_idx, cursorS, cursorD);
    scan_a_kernel<<<dim3(NBLK, 2), 256, 0, stream>>>(cursorS, cursorD,
                                                     rowptrS, rowptrD, bsum);
    scan_b_kernel<<<1, 256, 0, stream>>>(rowptrS, rowptrD, bsum, cursorS, cursorD);
    fill_kernel<<<(N_EDGES + 255) / 256, 256, 0, stream>>>(edge_idx, cursorS,
                                                           eperm, dst2);
    pos_kernel<<<(N_EDGES + 255) / 256, 256, 0, stream>>>(dst2, cursorD, pos);
    permute_ef_kernel<<<(N_EDGES * EDGE_DIM + 255) / 256, 256, 0, stream>>>(
        edge_feat, eperm, ef2);

    // ---- h0 ----
    node_proj_kernel<<<(N_NODES * H + 255) / 256, 256, 0, stream>>>(
        node_feat, W_np, b_np, h);

    // ---- 3 propagation steps ----
    for (int step = 0; step < STEPS; ++step) {
        u_precompute_kernel<<<313, 576, 0, stream>>>(W_e, b_e, h, U);
        edge_msg_kernel<<<(N_NODES * H + 255) / 256, 256, 0, stream>>>(
            rowptrS, pos, ef2, U, msg2);
        float* dst_h = (step == STEPS - 1) ? out : h;
        gather_gru_kernel<<<256, 256, 0, stream>>>(
            rowptrD, msg2, W_ih, W_hh, b_ih, b_hh, h, dst_h);
    }
}

// Round 7
// 441.744 us; speedup vs baseline: 1.1119x; 1.1119x over previous
//
#include <hip/hip_runtime.h>
#include <math.h>

#define N_NODES 20000
#define N_EDGES 160000
#define NODE_DIM 64
#define EDGE_DIM 16
#define H 32
#define STEPS 3
#define UROW 544   // U[v][c]: c = i*16+d for c<512 (i=c>>4,d=c&15); c=512+i is bias plane
#define NBLK 79    // ceil(20000/256)
#define WSTR 97    // padded LDS stride for 32x96 weight tiles (97%32=1 -> conflict-free)

// ---------------------------------------------------------------------------
// One-time build: src-CSR (rowptrS), dst-CSR (rowptrD), and in ONE fill pass:
// pos[slot] = dst-sorted slot of src-sorted edge, ef2 = ef in src-sorted order.
// ---------------------------------------------------------------------------
__global__ void hist2_kernel(const int* __restrict__ ei,
                             int* __restrict__ degS, int* __restrict__ degD) {
    int e = blockIdx.x * 256 + threadIdx.x;
    if (e < N_EDGES) {
        atomicAdd(&degS[ei[e]], 1);
        atomicAdd(&degD[ei[N_EDGES + e]], 1);
    }
}

// grid (NBLK, 2): y=0 scans degS->rowptrS, y=1 scans degD->rowptrD
__global__ void scan_a_kernel(const int* __restrict__ degS,
                              const int* __restrict__ degD,
                              int* __restrict__ rowptrS,
                              int* __restrict__ rowptrD,
                              int* __restrict__ bsum) {
    __shared__ int s[256];
    const int* deg = blockIdx.y ? degD : degS;
    int* part      = blockIdx.y ? rowptrD : rowptrS;
    int v = blockIdx.x * 256 + threadIdx.x;
    int x = (v < N_NODES) ? deg[v] : 0;
    s[threadIdx.x] = x;
    __syncthreads();
    for (int off = 1; off < 256; off <<= 1) {
        int t = (threadIdx.x >= off) ? s[threadIdx.x - off] : 0;
        __syncthreads();
        s[threadIdx.x] += t;
        __syncthreads();
    }
    if (v < N_NODES) part[v] = s[threadIdx.x] - x;
    if (threadIdx.x == 255) bsum[blockIdx.y * NBLK + blockIdx.x] = s[255];
}

// single block: finish both scans, seed both cursors
__global__ void scan_b_kernel(int* __restrict__ rowptrS,
                              int* __restrict__ rowptrD,
                              const int* __restrict__ bsum,
                              int* __restrict__ cursorS,
                              int* __restrict__ cursorD) {
    __shared__ int boff[2 * NBLK];
    if (threadIdx.x == 0) {
        for (int a = 0; a < 2; ++a) {
            int run = 0;
            for (int b = 0; b < NBLK; ++b) {
                boff[a * NBLK + b] = run;
                run += bsum[a * NBLK + b];
            }
        }
    }
    __syncthreads();
    for (int v = threadIdx.x; v < N_NODES; v += 256) {
        int rs = rowptrS[v] + boff[v >> 8];
        int rd = rowptrD[v] + boff[NBLK + (v >> 8)];
        rowptrS[v] = rs; cursorS[v] = rs;
        rowptrD[v] = rd; cursorD[v] = rd;
    }
    if (threadIdx.x == 0) {
        rowptrS[N_NODES] = N_EDGES;
        rowptrD[N_NODES] = N_EDGES;
    }
}

// one pass: src-slot assignment + dst-rank (pos) + ef permutation
__global__ void fill_kernel(const int* __restrict__ ei,
                            const float* __restrict__ ef,
                            int* __restrict__ cursorS,
                            int* __restrict__ cursorD,
                            int* __restrict__ pos,
                            float* __restrict__ ef2) {
    int e = blockIdx.x * 256 + threadIdx.x;
    if (e < N_EDGES) {
        int s  = ei[e];
        int dd = ei[N_EDGES + e];
        int slot = atomicAdd(&cursorS[s], 1);
        pos[slot] = atomicAdd(&cursorD[dd], 1);
        const float4* __restrict__ src = (const float4*)(ef + (size_t)e * EDGE_DIM);
        float4* __restrict__ dst = (float4*)(ef2 + (size_t)slot * EDGE_DIM);
        dst[0] = src[0]; dst[1] = src[1]; dst[2] = src[2]; dst[3] = src[3];
    }
}

// ---------------------------------------------------------------------------
// node projection: h = node_feat @ W_np.T + b_np
// ---------------------------------------------------------------------------
__global__ void node_proj_kernel(const float* __restrict__ nf,
                                 const float* __restrict__ W,
                                 const float* __restrict__ b,
                                 float* __restrict__ h) {
    int tid = blockIdx.x * blockDim.x + threadIdx.x;
    if (tid >= N_NODES * H) return;
    int v = tid >> 5;
    int i = tid & 31;
    const float* __restrict__ row = nf + v * NODE_DIM;
    const float* __restrict__ w   = W + i * NODE_DIM;
    float acc = b[i];
#pragma unroll
    for (int d = 0; d < NODE_DIM; ++d) acc = fmaf(row[d], w[d], acc);
    h[tid] = acc;
}

// ---------------------------------------------------------------------------
// U precompute v3 (unchanged — measured adequate):
//   U[v, c] = sum_k Wx[k][c] * h[v,k], W in registers, h via LDS broadcast.
// ---------------------------------------------------------------------------
__global__ __launch_bounds__(576)
void u_precompute_kernel(const float* __restrict__ We,
                         const float* __restrict__ be,
                         const float* __restrict__ h,
                         float* __restrict__ U) {
    __shared__ float hs[32 * 32];   // 4 KB
    int t = threadIdx.x;
    int c = t;

    float wreg[32];
    if (c < 512) {
        int i = c >> 4, d = c & 15;
#pragma unroll
        for (int k = 0; k < H; ++k) wreg[k] = We[(i * H + k) * EDGE_DIM + d];
    } else if (c < UROW) {
        int i = c - 512;
#pragma unroll
        for (int k = 0; k < H; ++k) wreg[k] = be[i * H + k];
    }

    for (int v0 = blockIdx.x * 32; v0 < N_NODES; v0 += gridDim.x * 32) {
        __syncthreads();
        for (int idx = t; idx < 32 * 32; idx += 576) hs[idx] = h[v0 * H + idx];
        __syncthreads();

        for (int n = 0; n < 32; n += 2) {
            const float4* __restrict__ hp0 = (const float4*)(hs + n * H);
            const float4* __restrict__ hp1 = (const float4*)(hs + (n + 1) * H);
            float a0 = 0.f, a1 = 0.f;
#pragma unroll
            for (int kk = 0; kk < 8; ++kk) {
                float4 q0 = hp0[kk];
                float4 q1 = hp1[kk];
                a0 = fmaf(wreg[4 * kk + 0], q0.x, a0);
                a1 = fmaf(wreg[4 * kk + 0], q1.x, a1);
                a0 = fmaf(wreg[4 * kk + 1], q0.y, a0);
                a1 = fmaf(wreg[4 * kk + 1], q1.y, a1);
                a0 = fmaf(wreg[4 * kk + 2], q0.z, a0);
                a1 = fmaf(wreg[4 * kk + 2], q1.z, a1);
                a0 = fmaf(wreg[4 * kk + 3], q0.w, a0);
                a1 = fmaf(wreg[4 * kk + 3], q1.w, a1);
            }
            if (c < UROW) {
                U[(size_t)(v0 + n)     * UROW + c] = a0;
                U[(size_t)(v0 + n + 1) * UROW + c] = a1;
            }
        }
    }
}

// ---------------------------------------------------------------------------
// Edge message (unchanged from R6): group per SRC node, U row in registers,
// result written to the dst-sorted slot pos[j] — no atomics.
// ---------------------------------------------------------------------------
__global__ __launch_bounds__(256)
void edge_msg_kernel(const int* __restrict__ rowptrS,
                     const int* __restrict__ pos,
                     const float* __restrict__ ef2,
                     const float* __restrict__ U,
                     float* __restrict__ msg2) {
    int lane = threadIdx.x & 31;
    int s    = (blockIdx.x * blockDim.x + threadIdx.x) >> 5;   // src node
    if (s >= N_NODES) return;

    int e0 = rowptrS[s];
    int e1 = rowptrS[s + 1];
    if (e0 == e1) return;

    const float* __restrict__ Up = U + (size_t)s * UROW;
    const float4* __restrict__ Ur = (const float4*)(Up + lane * EDGE_DIM);
    float4 u0 = Ur[0];
    float4 u1 = Ur[1];
    float4 u2 = Ur[2];
    float4 u3 = Ur[3];
    float bias = Up[512 + lane];

    for (int j = e0; j < e1; ++j) {
        float efv = (lane < EDGE_DIM) ? ef2[j * EDGE_DIM + lane] : 0.f;
        int slot = pos[j];
        float msg = bias;
        msg = fmaf(__shfl(efv,  0, 32), u0.x, msg);
        msg = fmaf(__shfl(efv,  1, 32), u0.y, msg);
        msg = fmaf(__shfl(efv,  2, 32), u0.z, msg);
        msg = fmaf(__shfl(efv,  3, 32), u0.w, msg);
        msg = fmaf(__shfl(efv,  4, 32), u1.x, msg);
        msg = fmaf(__shfl(efv,  5, 32), u1.y, msg);
        msg = fmaf(__shfl(efv,  6, 32), u1.z, msg);
        msg = fmaf(__shfl(efv,  7, 32), u1.w, msg);
        msg = fmaf(__shfl(efv,  8, 32), u2.x, msg);
        msg = fmaf(__shfl(efv,  9, 32), u2.y, msg);
        msg = fmaf(__shfl(efv, 10, 32), u2.z, msg);
        msg = fmaf(__shfl(efv, 11, 32), u2.w, msg);
        msg = fmaf(__shfl(efv, 12, 32), u3.x, msg);
        msg = fmaf(__shfl(efv, 13, 32), u3.y, msg);
        msg = fmaf(__shfl(efv, 14, 32), u3.z, msg);
        msg = fmaf(__shfl(efv, 15, 32), u3.w, msg);
        msg2[(size_t)slot * H + lane] = msg;
    }
}

// ---------------------------------------------------------------------------
// Fused gather + GRU v2: 2500 blocks, one 32-lane group per dst node (no
// grid loop). Gather unrolled x2 with independent partial sums. Weight
// tiles staged with stride-97 padding: writes (fixed row, k=0..31) hit banks
// (k+row)%32 — conflict-free; reads (fixed k, lane=0..31) likewise.
// ---------------------------------------------------------------------------
__global__ __launch_bounds__(256)
void gather_gru_kernel(const int* __restrict__ rowptrD,
                       const float* __restrict__ msg2,
                       const float* __restrict__ Wih,
                       const float* __restrict__ Whh,
                       const float* __restrict__ bih,
                       const float* __restrict__ bhh,
                       const float* __restrict__ h,
                       float* __restrict__ hout) {
    __shared__ float WihT[H * WSTR];   // [k*97 + gate*32 + i]
    __shared__ float WhhT[H * WSTR];
    for (int idx = threadIdx.x; idx < 3 * H * H; idx += 256) {
        int row = idx >> 5;
        int k   = idx & 31;
        WihT[k * WSTR + row] = Wih[idx];
        WhhT[k * WSTR + row] = Whh[idx];
    }
    __syncthreads();

    int lane = threadIdx.x & 31;
    int v    = (blockIdx.x * blockDim.x + threadIdx.x) >> 5;   // dst node
    if (v >= N_NODES) return;

    int s0 = rowptrD[v];
    int s1 = rowptrD[v + 1];
    float m0 = 0.f, m1 = 0.f;
    int slot = s0;
    for (; slot + 2 <= s1; slot += 2) {
        m0 += msg2[(size_t)slot * H + lane];
        m1 += msg2[(size_t)(slot + 1) * H + lane];
    }
    if (slot < s1) m0 += msg2[(size_t)slot * H + lane];
    float mv = m0 + m1;

    float hv = h[v * H + lane];
    float ir = bih[lane], iz = bih[H + lane], in_ = bih[2 * H + lane];
    float hr = bhh[lane], hz = bhh[H + lane], hn  = bhh[2 * H + lane];
#pragma unroll
    for (int k = 0; k < H; ++k) {
        float mk = __shfl(mv, k, 32);
        float hk = __shfl(hv, k, 32);
        ir  = fmaf(WihT[k * WSTR + lane],          mk, ir);
        iz  = fmaf(WihT[k * WSTR + H + lane],      mk, iz);
        in_ = fmaf(WihT[k * WSTR + 2 * H + lane],  mk, in_);
        hr  = fmaf(WhhT[k * WSTR + lane],          hk, hr);
        hz  = fmaf(WhhT[k * WSTR + H + lane],      hk, hz);
        hn  = fmaf(WhhT[k * WSTR + 2 * H + lane],  hk, hn);
    }
    float r  = 1.f / (1.f + __expf(-(ir + hr)));
    float z  = 1.f / (1.f + __expf(-(iz + hz)));
    float nn = tanhf(in_ + r * hn);
    hout[v * H + lane] = (1.f - z) * nn + z * hv;
}

// ---------------------------------------------------------------------------
extern "C" void kernel_launch(void* const* d_in, const int* in_sizes, int n_in,
                              void* d_out, int out_size, void* d_ws, size_t ws_size,
                              hipStream_t stream) {
    const float* node_feat = (const float*)d_in[0];
    const int*   edge_idx  = (const int*)  d_in[1];
    const float* edge_feat = (const float*)d_in[2];
    const float* W_np      = (const float*)d_in[3];
    const float* b_np      = (const float*)d_in[4];
    const float* W_e       = (const float*)d_in[5];
    const float* b_e       = (const float*)d_in[6];
    const float* W_ih      = (const float*)d_in[7];
    const float* W_hh      = (const float*)d_in[8];
    const float* b_ih      = (const float*)d_in[9];
    const float* b_hh      = (const float*)d_in[10];

    float* h       = (float*)d_ws;                          // N*H
    float* U       = h + (size_t)N_NODES * H;               // N*544
    float* ef2     = U + (size_t)N_NODES * UROW;            // E*16
    float* msg2    = ef2 + (size_t)N_EDGES * EDGE_DIM;      // E*32
    int*   rowptrS = (int*)(msg2 + (size_t)N_EDGES * H);    // N+1
    int*   rowptrD = rowptrS + (N_NODES + 1);               // N+1
    int*   cursorS = rowptrD + (N_NODES + 1);               // N  (also degS)
    int*   cursorD = cursorS + N_NODES;                     // N  (also degD)
    int*   bsum    = cursorD + N_NODES;                     // 2*NBLK
    int*   pos     = bsum + 2 * NBLK;                       // E
    float* out     = (float*)d_out;

    // ---- one-time: build src-CSR, dst-CSR, pos, ef2 ----
    hipMemsetAsync(cursorS, 0, 2 * N_NODES * sizeof(int), stream);  // S+D adjacent
    hist2_kernel<<<(N_EDGES + 255) / 256, 256, 0, stream>>>(edge_idx, cursorS, cursorD);
    scan_a_kernel<<<dim3(NBLK, 2), 256, 0, stream>>>(cursorS, cursorD,
                                                     rowptrS, rowptrD, bsum);
    scan_b_kernel<<<1, 256, 0, stream>>>(rowptrS, rowptrD, bsum, cursorS, cursorD);
    fill_kernel<<<(N_EDGES + 255) / 256, 256, 0, stream>>>(edge_idx, edge_feat,
                                                           cursorS, cursorD,
                                                           pos, ef2);

    // ---- h0 ----
    node_proj_kernel<<<(N_NODES * H + 255) / 256, 256, 0, stream>>>(
        node_feat, W_np, b_np, h);

    // ---- 3 propagation steps ----
    for (int step = 0; step < STEPS; ++step) {
        u_precompute_kernel<<<313, 576, 0, stream>>>(W_e, b_e, h, U);
        edge_msg_kernel<<<(N_NODES * H + 255) / 256, 256, 0, stream>>>(
            rowptrS, pos, ef2, U, msg2);
        float* dst_h = (step == STEPS - 1) ? out : h;
        gather_gru_kernel<<<(N_NODES * H + 255) / 256, 256, 0, stream>>>(
            rowptrD, msg2, W_ih, W_hh, b_ih, b_hh, h, dst_h);
    }
}

// Round 8
// 412.180 us; speedup vs baseline: 1.1917x; 1.0717x over previous
//
#include <hip/hip_runtime.h>
#include <math.h>

#define N_NODES 20000
#define N_EDGES 160000
#define NODE_DIM 64
#define EDGE_DIM 16
#define H 32
#define STEPS 3
#define UROW 544   // U[v][c]: c = i*16+d for c<512 (i=c>>4,d=c&15); c=512+i is bias plane
#define NBLK 79    // ceil(20000/256)
#define WS4 772    // gather_gru weight LDS stride per k4: 192 rows*4 + 4 pad

// ---------------------------------------------------------------------------
// One-time build: src-CSR (rowptrS), dst-CSR (rowptrD), and in ONE fill pass:
// pos[slot] = dst-sorted slot of src-sorted edge, ef2 = ef in src-sorted order.
// ---------------------------------------------------------------------------
__global__ void hist2_kernel(const int* __restrict__ ei,
                             int* __restrict__ degS, int* __restrict__ degD) {
    int e = blockIdx.x * 256 + threadIdx.x;
    if (e < N_EDGES) {
        atomicAdd(&degS[ei[e]], 1);
        atomicAdd(&degD[ei[N_EDGES + e]], 1);
    }
}

// grid (NBLK, 2): y=0 scans degS->rowptrS, y=1 scans degD->rowptrD
__global__ void scan_a_kernel(const int* __restrict__ degS,
                              const int* __restrict__ degD,
                              int* __restrict__ rowptrS,
                              int* __restrict__ rowptrD,
                              int* __restrict__ bsum) {
    __shared__ int s[256];
    const int* deg = blockIdx.y ? degD : degS;
    int* part      = blockIdx.y ? rowptrD : rowptrS;
    int v = blockIdx.x * 256 + threadIdx.x;
    int x = (v < N_NODES) ? deg[v] : 0;
    s[threadIdx.x] = x;
    __syncthreads();
    for (int off = 1; off < 256; off <<= 1) {
        int t = (threadIdx.x >= off) ? s[threadIdx.x - off] : 0;
        __syncthreads();
        s[threadIdx.x] += t;
        __syncthreads();
    }
    if (v < N_NODES) part[v] = s[threadIdx.x] - x;
    if (threadIdx.x == 255) bsum[blockIdx.y * NBLK + blockIdx.x] = s[255];
}

// single block: finish both scans, seed both cursors
__global__ void scan_b_kernel(int* __restrict__ rowptrS,
                              int* __restrict__ rowptrD,
                              const int* __restrict__ bsum,
                              int* __restrict__ cursorS,
                              int* __restrict__ cursorD) {
    __shared__ int boff[2 * NBLK];
    if (threadIdx.x == 0) {
        for (int a = 0; a < 2; ++a) {
            int run = 0;
            for (int b = 0; b < NBLK; ++b) {
                boff[a * NBLK + b] = run;
                run += bsum[a * NBLK + b];
            }
        }
    }
    __syncthreads();
    for (int v = threadIdx.x; v < N_NODES; v += 256) {
        int rs = rowptrS[v] + boff[v >> 8];
        int rd = rowptrD[v] + boff[NBLK + (v >> 8)];
        rowptrS[v] = rs; cursorS[v] = rs;
        rowptrD[v] = rd; cursorD[v] = rd;
    }
    if (threadIdx.x == 0) {
        rowptrS[N_NODES] = N_EDGES;
        rowptrD[N_NODES] = N_EDGES;
    }
}

// one pass: src-slot assignment + dst-rank (pos) + ef permutation
__global__ void fill_kernel(const int* __restrict__ ei,
                            const float* __restrict__ ef,
                            int* __restrict__ cursorS,
                            int* __restrict__ cursorD,
                            int* __restrict__ pos,
                            float* __restrict__ ef2) {
    int e = blockIdx.x * 256 + threadIdx.x;
    if (e < N_EDGES) {
        int s  = ei[e];
        int dd = ei[N_EDGES + e];
        int slot = atomicAdd(&cursorS[s], 1);
        pos[slot] = atomicAdd(&cursorD[dd], 1);
        const float4* __restrict__ src = (const float4*)(ef + (size_t)e * EDGE_DIM);
        float4* __restrict__ dst = (float4*)(ef2 + (size_t)slot * EDGE_DIM);
        dst[0] = src[0]; dst[1] = src[1]; dst[2] = src[2]; dst[3] = src[3];
    }
}

// ---------------------------------------------------------------------------
// node projection: h = node_feat @ W_np.T + b_np
// ---------------------------------------------------------------------------
__global__ void node_proj_kernel(const float* __restrict__ nf,
                                 const float* __restrict__ W,
                                 const float* __restrict__ b,
                                 float* __restrict__ h) {
    int tid = blockIdx.x * blockDim.x + threadIdx.x;
    if (tid >= N_NODES * H) return;
    int v = tid >> 5;
    int i = tid & 31;
    const float* __restrict__ row = nf + v * NODE_DIM;
    const float* __restrict__ w   = W + i * NODE_DIM;
    float acc = b[i];
#pragma unroll
    for (int d = 0; d < NODE_DIM; ++d) acc = fmaf(row[d], w[d], acc);
    h[tid] = acc;
}

// ---------------------------------------------------------------------------
// U precompute v3 (unchanged — measured adequate):
//   U[v, c] = sum_k Wx[k][c] * h[v,k], W in registers, h via LDS broadcast.
// ---------------------------------------------------------------------------
__global__ __launch_bounds__(576)
void u_precompute_kernel(const float* __restrict__ We,
                         const float* __restrict__ be,
                         const float* __restrict__ h,
                         float* __restrict__ U) {
    __shared__ float hs[32 * 32];   // 4 KB
    int t = threadIdx.x;
    int c = t;

    float wreg[32];
    if (c < 512) {
        int i = c >> 4, d = c & 15;
#pragma unroll
        for (int k = 0; k < H; ++k) wreg[k] = We[(i * H + k) * EDGE_DIM + d];
    } else if (c < UROW) {
        int i = c - 512;
#pragma unroll
        for (int k = 0; k < H; ++k) wreg[k] = be[i * H + k];
    }

    for (int v0 = blockIdx.x * 32; v0 < N_NODES; v0 += gridDim.x * 32) {
        __syncthreads();
        for (int idx = t; idx < 32 * 32; idx += 576) hs[idx] = h[v0 * H + idx];
        __syncthreads();

        for (int n = 0; n < 32; n += 2) {
            const float4* __restrict__ hp0 = (const float4*)(hs + n * H);
            const float4* __restrict__ hp1 = (const float4*)(hs + (n + 1) * H);
            float a0 = 0.f, a1 = 0.f;
#pragma unroll
            for (int kk = 0; kk < 8; ++kk) {
                float4 q0 = hp0[kk];
                float4 q1 = hp1[kk];
                a0 = fmaf(wreg[4 * kk + 0], q0.x, a0);
                a1 = fmaf(wreg[4 * kk + 0], q1.x, a1);
                a0 = fmaf(wreg[4 * kk + 1], q0.y, a0);
                a1 = fmaf(wreg[4 * kk + 1], q1.y, a1);
                a0 = fmaf(wreg[4 * kk + 2], q0.z, a0);
                a1 = fmaf(wreg[4 * kk + 2], q1.z, a1);
                a0 = fmaf(wreg[4 * kk + 3], q0.w, a0);
                a1 = fmaf(wreg[4 * kk + 3], q1.w, a1);
            }
            if (c < UROW) {
                U[(size_t)(v0 + n)     * UROW + c] = a0;
                U[(size_t)(v0 + n + 1) * UROW + c] = a1;
            }
        }
    }
}

// ---------------------------------------------------------------------------
// Edge message (unchanged from R7): group per SRC node, U row in registers,
// result written to the dst-sorted slot pos[j] — no atomics.
// ---------------------------------------------------------------------------
__global__ __launch_bounds__(256)
void edge_msg_kernel(const int* __restrict__ rowptrS,
                     const int* __restrict__ pos,
                     const float* __restrict__ ef2,
                     const float* __restrict__ U,
                     float* __restrict__ msg2) {
    int lane = threadIdx.x & 31;
    int s    = (blockIdx.x * blockDim.x + threadIdx.x) >> 5;   // src node
    if (s >= N_NODES) return;

    int e0 = rowptrS[s];
    int e1 = rowptrS[s + 1];
    if (e0 == e1) return;

    const float* __restrict__ Up = U + (size_t)s * UROW;
    const float4* __restrict__ Ur = (const float4*)(Up + lane * EDGE_DIM);
    float4 u0 = Ur[0];
    float4 u1 = Ur[1];
    float4 u2 = Ur[2];
    float4 u3 = Ur[3];
    float bias = Up[512 + lane];

    for (int j = e0; j < e1; ++j) {
        float efv = (lane < EDGE_DIM) ? ef2[j * EDGE_DIM + lane] : 0.f;
        int slot = pos[j];
        float msg = bias;
        msg = fmaf(__shfl(efv,  0, 32), u0.x, msg);
        msg = fmaf(__shfl(efv,  1, 32), u0.y, msg);
        msg = fmaf(__shfl(efv,  2, 32), u0.z, msg);
        msg = fmaf(__shfl(efv,  3, 32), u0.w, msg);
        msg = fmaf(__shfl(efv,  4, 32), u1.x, msg);
        msg = fmaf(__shfl(efv,  5, 32), u1.y, msg);
        msg = fmaf(__shfl(efv,  6, 32), u1.z, msg);
        msg = fmaf(__shfl(efv,  7, 32), u1.w, msg);
        msg = fmaf(__shfl(efv,  8, 32), u2.x, msg);
        msg = fmaf(__shfl(efv,  9, 32), u2.y, msg);
        msg = fmaf(__shfl(efv, 10, 32), u2.z, msg);
        msg = fmaf(__shfl(efv, 11, 32), u2.w, msg);
        msg = fmaf(__shfl(efv, 12, 32), u3.x, msg);
        msg = fmaf(__shfl(efv, 13, 32), u3.y, msg);
        msg = fmaf(__shfl(efv, 14, 32), u3.z, msg);
        msg = fmaf(__shfl(efv, 15, 32), u3.w, msg);
        msg2[(size_t)slot * H + lane] = msg;
    }
}

// ---------------------------------------------------------------------------
// Fused gather + GRU v3: 625 blocks x 8 groups x 4 nodes = 20000.
// Each 32-lane group processes 4 nodes so every LDS weight read feeds 4 FMAs.
// Weights packed 4-k-wide: WT[k4*WS4 + row*4 + kp], rows 0-95 = W_ih,
// 96-191 = W_hh. Reads are ds_read_b128 at lane-stride 16 B (conflict-free);
// staging writes hit banks (4*row+4*k4+kp)%32 = all-distinct (conflict-free).
// 24 independent accumulators (4 nodes x 6 gates) for ILP.
// ---------------------------------------------------------------------------
__global__ __launch_bounds__(256)
void gather_gru_kernel(const int* __restrict__ rowptrD,
                       const float* __restrict__ msg2,
                       const float* __restrict__ Wih,
                       const float* __restrict__ Whh,
                       const float* __restrict__ bih,
                       const float* __restrict__ bhh,
                       const float* __restrict__ h,
                       float* __restrict__ hout) {
    __shared__ float WT[8 * WS4];   // 24704 B
    for (int idx = threadIdx.x; idx < 3 * H * H; idx += 256) {
        int row = idx >> 5;          // 0..95
        int k   = idx & 31;
        WT[(k >> 2) * WS4 + row * 4 + (k & 3)]        = Wih[idx];
        WT[(k >> 2) * WS4 + (96 + row) * 4 + (k & 3)] = Whh[idx];
    }
    __syncthreads();

    int lane = threadIdx.x & 31;
    int grp  = threadIdx.x >> 5;              // 0..7
    int v0   = blockIdx.x * 32 + grp * 4;     // 4 nodes per group, exact cover

    // ---- gather m for 4 nodes (dst-sorted msg2 slots, coalesced rows) ----
    float mv[4], hv[4];
#pragma unroll
    for (int n = 0; n < 4; ++n) {
        int v  = v0 + n;
        int s0 = rowptrD[v];
        int s1 = rowptrD[v + 1];
        float acc = 0.f;
        for (int s = s0; s < s1; ++s) acc += msg2[(size_t)s * H + lane];
        mv[n] = acc;
        hv[n] = h[v * H + lane];
    }

    float a[4][6];   // per node: [ir iz in hr hz hn]
#pragma unroll
    for (int n = 0; n < 4; ++n)
#pragma unroll
        for (int g = 0; g < 6; ++g) a[n][g] = 0.f;

#pragma unroll 2
    for (int k4 = 0; k4 < 8; ++k4) {
        const float4* __restrict__ Wp = (const float4*)(WT + k4 * WS4);
        float4 wi0 = Wp[lane];
        float4 wi1 = Wp[32 + lane];
        float4 wi2 = Wp[64 + lane];
        float4 wh0 = Wp[96 + lane];
        float4 wh1 = Wp[128 + lane];
        float4 wh2 = Wp[160 + lane];
#pragma unroll
        for (int kp = 0; kp < 4; ++kp) {
            int k = k4 * 4 + kp;
            float f_wi0 = ((const float*)&wi0)[kp];
            float f_wi1 = ((const float*)&wi1)[kp];
            float f_wi2 = ((const float*)&wi2)[kp];
            float f_wh0 = ((const float*)&wh0)[kp];
            float f_wh1 = ((const float*)&wh1)[kp];
            float f_wh2 = ((const float*)&wh2)[kp];
#pragma unroll
            for (int n = 0; n < 4; ++n) {
                float mk = __shfl(mv[n], k, 32);
                float hk = __shfl(hv[n], k, 32);
                a[n][0] = fmaf(f_wi0, mk, a[n][0]);
                a[n][1] = fmaf(f_wi1, mk, a[n][1]);
                a[n][2] = fmaf(f_wi2, mk, a[n][2]);
                a[n][3] = fmaf(f_wh0, hk, a[n][3]);
                a[n][4] = fmaf(f_wh1, hk, a[n][4]);
                a[n][5] = fmaf(f_wh2, hk, a[n][5]);
            }
        }
    }

    // ---- epilogue ----
    float bi0 = bih[lane], bi1 = bih[H + lane], bi2 = bih[2 * H + lane];
    float bh0 = bhh[lane], bh1 = bhh[H + lane], bh2 = bhh[2 * H + lane];
#pragma unroll
    for (int n = 0; n < 4; ++n) {
        float r  = 1.f / (1.f + __expf(-(a[n][0] + bi0 + a[n][3] + bh0)));
        float z  = 1.f / (1.f + __expf(-(a[n][1] + bi1 + a[n][4] + bh1)));
        float nn = tanhf(a[n][2] + bi2 + r * (a[n][5] + bh2));
        hout[(v0 + n) * H + lane] = (1.f - z) * nn + z * hv[n];
    }
}

// ---------------------------------------------------------------------------
extern "C" void kernel_launch(void* const* d_in, const int* in_sizes, int n_in,
                              void* d_out, int out_size, void* d_ws, size_t ws_size,
                              hipStream_t stream) {
    const float* node_feat = (const float*)d_in[0];
    const int*   edge_idx  = (const int*)  d_in[1];
    const float* edge_feat = (const float*)d_in[2];
    const float* W_np      = (const float*)d_in[3];
    const float* b_np      = (const float*)d_in[4];
    const float* W_e       = (const float*)d_in[5];
    const float* b_e       = (const float*)d_in[6];
    const float* W_ih      = (const float*)d_in[7];
    const float* W_hh      = (const float*)d_in[8];
    const float* b_ih      = (const float*)d_in[9];
    const float* b_hh      = (const float*)d_in[10];

    float* h       = (float*)d_ws;                          // N*H
    float* U       = h + (size_t)N_NODES * H;               // N*544
    float* ef2     = U + (size_t)N_NODES * UROW;            // E*16
    float* msg2    = ef2 + (size_t)N_EDGES * EDGE_DIM;      // E*32
    int*   rowptrS = (int*)(msg2 + (size_t)N_EDGES * H);    // N+1
    int*   rowptrD = rowptrS + (N_NODES + 1);               // N+1
    int*   cursorS = rowptrD + (N_NODES + 1);               // N  (also degS)
    int*   cursorD = cursorS + N_NODES;                     // N  (also degD)
    int*   bsum    = cursorD + N_NODES;                     // 2*NBLK
    int*   pos     = bsum + 2 * NBLK;                       // E
    float* out     = (float*)d_out;

    // ---- one-time: build src-CSR, dst-CSR, pos, ef2 ----
    hipMemsetAsync(cursorS, 0, 2 * N_NODES * sizeof(int), stream);  // S+D adjacent
    hist2_kernel<<<(N_EDGES + 255) / 256, 256, 0, stream>>>(edge_idx, cursorS, cursorD);
    scan_a_kernel<<<dim3(NBLK, 2), 256, 0, stream>>>(cursorS, cursorD,
                                                     rowptrS, rowptrD, bsum);
    scan_b_kernel<<<1, 256, 0, stream>>>(rowptrS, rowptrD, bsum, cursorS, cursorD);
    fill_kernel<<<(N_EDGES + 255) / 256, 256, 0, stream>>>(edge_idx, edge_feat,
                                                           cursorS, cursorD,
                                                           pos, ef2);

    // ---- h0 ----
    node_proj_kernel<<<(N_NODES * H + 255) / 256, 256, 0, stream>>>(
        node_feat, W_np, b_np, h);

    // ---- 3 propagation steps ----
    for (int step = 0; step < STEPS; ++step) {
        u_precompute_kernel<<<313, 576, 0, stream>>>(W_e, b_e, h, U);
        edge_msg_kernel<<<(N_NODES * H + 255) / 256, 256, 0, stream>>>(
            rowptrS, pos, ef2, U, msg2);
        float* dst_h = (step == STEPS - 1) ? out : h;
        gather_gru_kernel<<<625, 256, 0, stream>>>(
            rowptrD, msg2, W_ih, W_hh, b_ih, b_hh, h, dst_h);
    }
}

// Round 9
// 388.052 us; speedup vs baseline: 1.2658x; 1.0622x over previous
//
#include <hip/hip_runtime.h>
#include <math.h>

#define N_NODES 20000
#define N_EDGES 160000
#define NODE_DIM 64
#define EDGE_DIM 16
#define H 32
#define STEPS 3
#define NBLK 79    // ceil(20000/256)
#define WS4 772    // gather_gru weight LDS stride per k4: 192 rows*4 + 4 pad
#define NB 16      // src nodes per fused_msg block
#define USTR 548   // LDS U-tile row stride (544 + 4 pad, float4-aligned)

// ---------------------------------------------------------------------------
// One-time build: src-CSR (rowptrS), dst-CSR (rowptrD), and in ONE fill pass:
// pos[slot] = dst-sorted slot of src-sorted edge, ef2 = ef in src-sorted order.
// ---------------------------------------------------------------------------
__global__ void hist2_kernel(const int* __restrict__ ei,
                             int* __restrict__ degS, int* __restrict__ degD) {
    int e = blockIdx.x * 256 + threadIdx.x;
    if (e < N_EDGES) {
        atomicAdd(&degS[ei[e]], 1);
        atomicAdd(&degD[ei[N_EDGES + e]], 1);
    }
}

__global__ void scan_a_kernel(const int* __restrict__ degS,
                              const int* __restrict__ degD,
                              int* __restrict__ rowptrS,
                              int* __restrict__ rowptrD,
                              int* __restrict__ bsum) {
    __shared__ int s[256];
    const int* deg = blockIdx.y ? degD : degS;
    int* part      = blockIdx.y ? rowptrD : rowptrS;
    int v = blockIdx.x * 256 + threadIdx.x;
    int x = (v < N_NODES) ? deg[v] : 0;
    s[threadIdx.x] = x;
    __syncthreads();
    for (int off = 1; off < 256; off <<= 1) {
        int t = (threadIdx.x >= off) ? s[threadIdx.x - off] : 0;
        __syncthreads();
        s[threadIdx.x] += t;
        __syncthreads();
    }
    if (v < N_NODES) part[v] = s[threadIdx.x] - x;
    if (threadIdx.x == 255) bsum[blockIdx.y * NBLK + blockIdx.x] = s[255];
}

__global__ void scan_b_kernel(int* __restrict__ rowptrS,
                              int* __restrict__ rowptrD,
                              const int* __restrict__ bsum,
                              int* __restrict__ cursorS,
                              int* __restrict__ cursorD) {
    __shared__ int boff[2 * NBLK];
    if (threadIdx.x == 0) {
        for (int a = 0; a < 2; ++a) {
            int run = 0;
            for (int b = 0; b < NBLK; ++b) {
                boff[a * NBLK + b] = run;
                run += bsum[a * NBLK + b];
            }
        }
    }
    __syncthreads();
    for (int v = threadIdx.x; v < N_NODES; v += 256) {
        int rs = rowptrS[v] + boff[v >> 8];
        int rd = rowptrD[v] + boff[NBLK + (v >> 8)];
        rowptrS[v] = rs; cursorS[v] = rs;
        rowptrD[v] = rd; cursorD[v] = rd;
    }
    if (threadIdx.x == 0) {
        rowptrS[N_NODES] = N_EDGES;
        rowptrD[N_NODES] = N_EDGES;
    }
}

__global__ void fill_kernel(const int* __restrict__ ei,
                            const float* __restrict__ ef,
                            int* __restrict__ cursorS,
                            int* __restrict__ cursorD,
                            int* __restrict__ pos,
                            float* __restrict__ ef2) {
    int e = blockIdx.x * 256 + threadIdx.x;
    if (e < N_EDGES) {
        int s  = ei[e];
        int dd = ei[N_EDGES + e];
        int slot = atomicAdd(&cursorS[s], 1);
        pos[slot] = atomicAdd(&cursorD[dd], 1);
        const float4* __restrict__ src = (const float4*)(ef + (size_t)e * EDGE_DIM);
        float4* __restrict__ dst = (float4*)(ef2 + (size_t)slot * EDGE_DIM);
        dst[0] = src[0]; dst[1] = src[1]; dst[2] = src[2]; dst[3] = src[3];
    }
}

// ---------------------------------------------------------------------------
// node projection: h = node_feat @ W_np.T + b_np
// ---------------------------------------------------------------------------
__global__ void node_proj_kernel(const float* __restrict__ nf,
                                 const float* __restrict__ W,
                                 const float* __restrict__ b,
                                 float* __restrict__ h) {
    int tid = blockIdx.x * blockDim.x + threadIdx.x;
    if (tid >= N_NODES * H) return;
    int v = tid >> 5;
    int i = tid & 31;
    const float* __restrict__ row = nf + v * NODE_DIM;
    const float* __restrict__ w   = W + i * NODE_DIM;
    float acc = b[i];
#pragma unroll
    for (int d = 0; d < NODE_DIM; ++d) acc = fmaf(row[d], w[d], acc);
    h[tid] = acc;
}

// ---------------------------------------------------------------------------
// FUSED message kernel: u_precompute + edge_msg in one block; the per-node
// matrix U[v] lives only in LDS (35 KB tile), never in global.
// Phase A (all 256 threads): thread t computes U cols c=t and c=t+256 for the
//   block's 16 src nodes (W in 64 regs); threads 0..31 also compute the bias
//   column 512+t. h rows staged in 2 KB LDS, read as same-address broadcast.
// Phase B (8 groups x 32 lanes, 2 src nodes each): lane i pulls
//   U[n, i*16..i*16+15]+bias from LDS into regs, then streams the src's
//   out-edges: coalesced ef2 read, pos-indexed scattered msg2 store.
//   Edge dot = 4 independent FMA chains, edges unrolled x2 for ILP.
// Grid: 1250 blocks x 16 nodes = 20000 exactly.
// ---------------------------------------------------------------------------
__global__ __launch_bounds__(256)
void fused_msg_kernel(const float* __restrict__ We,
                      const float* __restrict__ be,
                      const float* __restrict__ h,
                      const int* __restrict__ rowptrS,
                      const int* __restrict__ pos,
                      const float* __restrict__ ef2,
                      float* __restrict__ msg2) {
    __shared__ float hs[NB * H];      // 2 KB
    __shared__ float Ut[NB * USTR];   // 35072 B

    int t = threadIdx.x;
    int c0 = t, c1 = t + 256;
    bool doB = (t < 32);

    float w0[32], w1[32], breg[32];
    {
        int i0 = c0 >> 4, d0 = c0 & 15;
        int i1 = c1 >> 4, d1 = c1 & 15;
#pragma unroll
        for (int k = 0; k < H; ++k) {
            w0[k] = We[(i0 * H + k) * EDGE_DIM + d0];
            w1[k] = We[(i1 * H + k) * EDGE_DIM + d1];
        }
        if (doB) {
#pragma unroll
            for (int k = 0; k < H; ++k) breg[k] = be[t * H + k];
        }
    }

    int vbase = blockIdx.x * NB;
    for (int idx = t; idx < NB * H; idx += 256) hs[idx] = h[vbase * H + idx];
    __syncthreads();

    // ---- Phase A: build U tile in LDS ----
    for (int n = 0; n < NB; ++n) {
        const float4* __restrict__ hp = (const float4*)(hs + n * H);
        float a0 = 0.f, a1 = 0.f, ab = 0.f;
#pragma unroll
        for (int kk = 0; kk < 8; ++kk) {
            float4 q = hp[kk];
            a0 = fmaf(w0[4 * kk + 0], q.x, a0);
            a1 = fmaf(w1[4 * kk + 0], q.x, a1);
            a0 = fmaf(w0[4 * kk + 1], q.y, a0);
            a1 = fmaf(w1[4 * kk + 1], q.y, a1);
            a0 = fmaf(w0[4 * kk + 2], q.z, a0);
            a1 = fmaf(w1[4 * kk + 2], q.z, a1);
            a0 = fmaf(w0[4 * kk + 3], q.w, a0);
            a1 = fmaf(w1[4 * kk + 3], q.w, a1);
            if (doB) {
                ab = fmaf(breg[4 * kk + 0], q.x, ab);
                ab = fmaf(breg[4 * kk + 1], q.y, ab);
                ab = fmaf(breg[4 * kk + 2], q.z, ab);
                ab = fmaf(breg[4 * kk + 3], q.w, ab);
            }
        }
        Ut[n * USTR + c0] = a0;
        Ut[n * USTR + c1] = a1;
        if (doB) Ut[n * USTR + 512 + t] = ab;
    }
    __syncthreads();

    // ---- Phase B: stream out-edges of the 16 src nodes ----
    int lane = t & 31;
    int grp  = t >> 5;   // 0..7

#pragma unroll
    for (int nn = 0; nn < 2; ++nn) {
        int n = grp * 2 + nn;
        int v = vbase + n;
        const float4* __restrict__ Ur = (const float4*)(Ut + n * USTR + lane * EDGE_DIM);
        float4 u0 = Ur[0];
        float4 u1 = Ur[1];
        float4 u2 = Ur[2];
        float4 u3 = Ur[3];
        float bias = Ut[n * USTR + 512 + lane];

        int e0 = rowptrS[v];
        int e1 = rowptrS[v + 1];

        int j = e0;
        for (; j + 2 <= e1; j += 2) {
            float efa = (lane < EDGE_DIM) ? ef2[(size_t)j * EDGE_DIM + lane] : 0.f;
            float efb = (lane < EDGE_DIM) ? ef2[(size_t)(j + 1) * EDGE_DIM + lane] : 0.f;
            int sa = pos[j];
            int sb = pos[j + 1];
            // edge a: 4 independent chains
            float aA = bias, aB = 0.f, aC = 0.f, aD = 0.f;
            aA = fmaf(__shfl(efa,  0, 32), u0.x, aA);
            aB = fmaf(__shfl(efa,  1, 32), u0.y, aB);
            aC = fmaf(__shfl(efa,  2, 32), u0.z, aC);
            aD = fmaf(__shfl(efa,  3, 32), u0.w, aD);
            aA = fmaf(__shfl(efa,  4, 32), u1.x, aA);
            aB = fmaf(__shfl(efa,  5, 32), u1.y, aB);
            aC = fmaf(__shfl(efa,  6, 32), u1.z, aC);
            aD = fmaf(__shfl(efa,  7, 32), u1.w, aD);
            aA = fmaf(__shfl(efa,  8, 32), u2.x, aA);
            aB = fmaf(__shfl(efa,  9, 32), u2.y, aB);
            aC = fmaf(__shfl(efa, 10, 32), u2.z, aC);
            aD = fmaf(__shfl(efa, 11, 32), u2.w, aD);
            aA = fmaf(__shfl(efa, 12, 32), u3.x, aA);
            aB = fmaf(__shfl(efa, 13, 32), u3.y, aB);
            aC = fmaf(__shfl(efa, 14, 32), u3.z, aC);
            aD = fmaf(__shfl(efa, 15, 32), u3.w, aD);
            // edge b
            float bA = bias, bB = 0.f, bC = 0.f, bD = 0.f;
            bA = fmaf(__shfl(efb,  0, 32), u0.x, bA);
            bB = fmaf(__shfl(efb,  1, 32), u0.y, bB);
            bC = fmaf(__shfl(efb,  2, 32), u0.z, bC);
            bD = fmaf(__shfl(efb,  3, 32), u0.w, bD);
            bA = fmaf(__shfl(efb,  4, 32), u1.x, bA);
            bB = fmaf(__shfl(efb,  5, 32), u1.y, bB);
            bC = fmaf(__shfl(efb,  6, 32), u1.z, bC);
            bD = fmaf(__shfl(efb,  7, 32), u1.w, bD);
            bA = fmaf(__shfl(efb,  8, 32), u2.x, bA);
            bB = fmaf(__shfl(efb,  9, 32), u2.y, bB);
            bC = fmaf(__shfl(efb, 10, 32), u2.z, bC);
            bD = fmaf(__shfl(efb, 11, 32), u2.w, bD);
            bA = fmaf(__shfl(efb, 12, 32), u3.x, bA);
            bB = fmaf(__shfl(efb, 13, 32), u3.y, bB);
            bC = fmaf(__shfl(efb, 14, 32), u3.z, bC);
            bD = fmaf(__shfl(efb, 15, 32), u3.w, bD);
            msg2[(size_t)sa * H + lane] = (aA + aB) + (aC + aD);
            msg2[(size_t)sb * H + lane] = (bA + bB) + (bC + bD);
        }
        if (j < e1) {
            float efa = (lane < EDGE_DIM) ? ef2[(size_t)j * EDGE_DIM + lane] : 0.f;
            int sa = pos[j];
            float aA = bias, aB = 0.f, aC = 0.f, aD = 0.f;
            aA = fmaf(__shfl(efa,  0, 32), u0.x, aA);
            aB = fmaf(__shfl(efa,  1, 32), u0.y, aB);
            aC = fmaf(__shfl(efa,  2, 32), u0.z, aC);
            aD = fmaf(__shfl(efa,  3, 32), u0.w, aD);
            aA = fmaf(__shfl(efa,  4, 32), u1.x, aA);
            aB = fmaf(__shfl(efa,  5, 32), u1.y, aB);
            aC = fmaf(__shfl(efa,  6, 32), u1.z, aC);
            aD = fmaf(__shfl(efa,  7, 32), u1.w, aD);
            aA = fmaf(__shfl(efa,  8, 32), u2.x, aA);
            aB = fmaf(__shfl(efa,  9, 32), u2.y, aB);
            aC = fmaf(__shfl(efa, 10, 32), u2.z, aC);
            aD = fmaf(__shfl(efa, 11, 32), u2.w, aD);
            aA = fmaf(__shfl(efa, 12, 32), u3.x, aA);
            aB = fmaf(__shfl(efa, 13, 32), u3.y, aB);
            aC = fmaf(__shfl(efa, 14, 32), u3.z, aC);
            aD = fmaf(__shfl(efa, 15, 32), u3.w, aD);
            msg2[(size_t)sa * H + lane] = (aA + aB) + (aC + aD);
        }
    }
}

// ---------------------------------------------------------------------------
// Fused gather + GRU v4: 1250 blocks x 8 groups x 2 nodes = 20000.
// Same b128-packed weight LDS as v3; 2 nodes/group doubles resident waves
// (5000 total, ~20/CU) to hide the msg2 gather latency.
// ---------------------------------------------------------------------------
__global__ __launch_bounds__(256)
void gather_gru_kernel(const int* __restrict__ rowptrD,
                       const float* __restrict__ msg2,
                       const float* __restrict__ Wih,
                       const float* __restrict__ Whh,
                       const float* __restrict__ bih,
                       const float* __restrict__ bhh,
                       const float* __restrict__ h,
                       float* __restrict__ hout) {
    __shared__ float WT[8 * WS4];   // 24704 B
    for (int idx = threadIdx.x; idx < 3 * H * H; idx += 256) {
        int row = idx >> 5;          // 0..95
        int k   = idx & 31;
        WT[(k >> 2) * WS4 + row * 4 + (k & 3)]        = Wih[idx];
        WT[(k >> 2) * WS4 + (96 + row) * 4 + (k & 3)] = Whh[idx];
    }
    __syncthreads();

    int lane = threadIdx.x & 31;
    int grp  = threadIdx.x >> 5;              // 0..7
    int v0   = blockIdx.x * 16 + grp * 2;     // 2 nodes per group, exact cover

    float mv[2], hv[2];
#pragma unroll
    for (int n = 0; n < 2; ++n) {
        int v  = v0 + n;
        int s0 = rowptrD[v];
        int s1 = rowptrD[v + 1];
        float acc0 = 0.f, acc1 = 0.f;
        int s = s0;
        for (; s + 2 <= s1; s += 2) {
            acc0 += msg2[(size_t)s * H + lane];
            acc1 += msg2[(size_t)(s + 1) * H + lane];
        }
        if (s < s1) acc0 += msg2[(size_t)s * H + lane];
        mv[n] = acc0 + acc1;
        hv[n] = h[v * H + lane];
    }

    float a[2][6];
#pragma unroll
    for (int n = 0; n < 2; ++n)
#pragma unroll
        for (int g = 0; g < 6; ++g) a[n][g] = 0.f;

#pragma unroll 2
    for (int k4 = 0; k4 < 8; ++k4) {
        const float4* __restrict__ Wp = (const float4*)(WT + k4 * WS4);
        float4 wi0 = Wp[lane];
        float4 wi1 = Wp[32 + lane];
        float4 wi2 = Wp[64 + lane];
        float4 wh0 = Wp[96 + lane];
        float4 wh1 = Wp[128 + lane];
        float4 wh2 = Wp[160 + lane];
#pragma unroll
        for (int kp = 0; kp < 4; ++kp) {
            int k = k4 * 4 + kp;
            float f_wi0 = ((const float*)&wi0)[kp];
            float f_wi1 = ((const float*)&wi1)[kp];
            float f_wi2 = ((const float*)&wi2)[kp];
            float f_wh0 = ((const float*)&wh0)[kp];
            float f_wh1 = ((const float*)&wh1)[kp];
            float f_wh2 = ((const float*)&wh2)[kp];
#pragma unroll
            for (int n = 0; n < 2; ++n) {
                float mk = __shfl(mv[n], k, 32);
                float hk = __shfl(hv[n], k, 32);
                a[n][0] = fmaf(f_wi0, mk, a[n][0]);
                a[n][1] = fmaf(f_wi1, mk, a[n][1]);
                a[n][2] = fmaf(f_wi2, mk, a[n][2]);
                a[n][3] = fmaf(f_wh0, hk, a[n][3]);
                a[n][4] = fmaf(f_wh1, hk, a[n][4]);
                a[n][5] = fmaf(f_wh2, hk, a[n][5]);
            }
        }
    }

    float bi0 = bih[lane], bi1 = bih[H + lane], bi2 = bih[2 * H + lane];
    float bh0 = bhh[lane], bh1 = bhh[H + lane], bh2 = bhh[2 * H + lane];
#pragma unroll
    for (int n = 0; n < 2; ++n) {
        float r  = 1.f / (1.f + __expf(-(a[n][0] + bi0 + a[n][3] + bh0)));
        float z  = 1.f / (1.f + __expf(-(a[n][1] + bi1 + a[n][4] + bh1)));
        float nn = tanhf(a[n][2] + bi2 + r * (a[n][5] + bh2));
        hout[(v0 + n) * H + lane] = (1.f - z) * nn + z * hv[n];
    }
}

// ---------------------------------------------------------------------------
extern "C" void kernel_launch(void* const* d_in, const int* in_sizes, int n_in,
                              void* d_out, int out_size, void* d_ws, size_t ws_size,
                              hipStream_t stream) {
    const float* node_feat = (const float*)d_in[0];
    const int*   edge_idx  = (const int*)  d_in[1];
    const float* edge_feat = (const float*)d_in[2];
    const float* W_np      = (const float*)d_in[3];
    const float* b_np      = (const float*)d_in[4];
    const float* W_e       = (const float*)d_in[5];
    const float* b_e       = (const float*)d_in[6];
    const float* W_ih      = (const float*)d_in[7];
    const float* W_hh      = (const float*)d_in[8];
    const float* b_ih      = (const float*)d_in[9];
    const float* b_hh      = (const float*)d_in[10];

    float* h       = (float*)d_ws;                          // N*H
    float* ef2     = h + (size_t)N_NODES * H;               // E*16
    float* msg2    = ef2 + (size_t)N_EDGES * EDGE_DIM;      // E*32
    int*   rowptrS = (int*)(msg2 + (size_t)N_EDGES * H);    // N+1
    int*   rowptrD = rowptrS + (N_NODES + 1);               // N+1
    int*   cursorS = rowptrD + (N_NODES + 1);               // N  (also degS)
    int*   cursorD = cursorS + N_NODES;                     // N  (also degD)
    int*   bsum    = cursorD + N_NODES;                     // 2*NBLK
    int*   pos     = bsum + 2 * NBLK;                       // E
    float* out     = (float*)d_out;

    // ---- one-time: build src-CSR, dst-CSR, pos, ef2 ----
    hipMemsetAsync(cursorS, 0, 2 * N_NODES * sizeof(int), stream);  // S+D adjacent
    hist2_kernel<<<(N_EDGES + 255) / 256, 256, 0, stream>>>(edge_idx, cursorS, cursorD);
    scan_a_kernel<<<dim3(NBLK, 2), 256, 0, stream>>>(cursorS, cursorD,
                                                     rowptrS, rowptrD, bsum);
    scan_b_kernel<<<1, 256, 0, stream>>>(rowptrS, rowptrD, bsum, cursorS, cursorD);
    fill_kernel<<<(N_EDGES + 255) / 256, 256, 0, stream>>>(edge_idx, edge_feat,
                                                           cursorS, cursorD,
                                                           pos, ef2);

    // ---- h0 ----
    node_proj_kernel<<<(N_NODES * H + 255) / 256, 256, 0, stream>>>(
        node_feat, W_np, b_np, h);

    // ---- 3 propagation steps ----
    for (int step = 0; step < STEPS; ++step) {
        fused_msg_kernel<<<N_NODES / NB, 256, 0, stream>>>(
            W_e, b_e, h, rowptrS, pos, ef2, msg2);
        float* dst_h = (step == STEPS - 1) ? out : h;
        gather_gru_kernel<<<1250, 256, 0, stream>>>(
            rowptrD, msg2, W_ih, W_hh, b_ih, b_hh, h, dst_h);
    }
}